// Round 1
// baseline (164.614 us; speedup 1.0000x reference)
//
#include <hip/hip_runtime.h>
#include <hip/hip_bf16.h>
#include <stdint.h>

// ---------------------------------------------------------------------------
// LatentMoE forward for MI355X (gfx950). bf16 MFMA internals, f32 accumulate.
// ---------------------------------------------------------------------------

using f32x4 = __attribute__((ext_vector_type(4))) float;
using s16x8 = __attribute__((ext_vector_type(8))) short;

#define MFMA_BF16(a, b, c) __builtin_amdgcn_mfma_f32_16x16x32_bf16((a), (b), (c), 0, 0, 0)

__device__ __forceinline__ unsigned short f2bf(float f) {
  union { float f; uint32_t u; } v; v.f = f;
  uint32_t u = v.u;
  u += 0x7FFFu + ((u >> 16) & 1u);   // round-to-nearest-even
  return (unsigned short)(u >> 16);
}
__device__ __forceinline__ float bf2f(unsigned short h) {
  union { uint32_t u; float f; } v; v.u = ((uint32_t)h) << 16;
  return v.f;
}
__device__ __forceinline__ float silu_f(float x) { return x / (1.f + expf(-x)); }

// ---------------------------------------------------------------------------
// Staging: global bf16 tile [128 rows x 32 k] -> LDS laid out [4][128][8]
// (kh-major blocks of 8 k-elems). Conflict-free ds_read_b128 on fragment loads,
// and each 16B chunk is contiguous in global memory => global_load_lds works.
// ---------------------------------------------------------------------------
__device__ __forceinline__ void stage_tile(const unsigned short* __restrict__ G, int ldg,
                                           int row0, int kt, unsigned short* lbuf,
                                           int wid, int lane) {
#pragma unroll
  for (int j = 0; j < 2; ++j) {
    int o = j * 4096 + wid * 1024 + lane * 16;      // byte offset in 8KB tile
    int kh = o >> 11;                               // 0..3
    int row = (o & 2047) >> 4;                      // 0..127
    const unsigned short* src = G + (size_t)(row0 + row) * ldg + kt * 32 + kh * 8;
    // LDS dest is wave-uniform base + lane*16 (HW behavior)
    __builtin_amdgcn_global_load_lds(
        (const __attribute__((address_space(1))) void*)src,
        (__attribute__((address_space(3))) void*)(lbuf + (size_t)(j * 2048 + wid * 512)),
        16, 0, 0);
  }
}

// ---------------------------------------------------------------------------
// 128x128 tile GEMM core: C[M,N] (+= Cadd) = A[M,K] * B[N,K]^T, bf16 in, f32 acc.
// 256 threads = 4 waves in 2x2; each wave owns a 64x64 subtile (4x4 16x16 frags).
// 2-phase prefetch: issue next-tile global_load_lds before ds_read+MFMA.
// ---------------------------------------------------------------------------
template <bool ADD_C, bool OUT_BF16>
__device__ __forceinline__ void gemm_core(const unsigned short* __restrict__ A, int lda,
                                          const unsigned short* __restrict__ B, int ldb,
                                          void* __restrict__ Cp, int ldc,
                                          const float* __restrict__ Cadd, int ldadd,
                                          int K, int m0, int n0,
                                          unsigned short* As, unsigned short* Bs) {
  const int tid = threadIdx.x;
  const int wid = tid >> 6, lane = tid & 63;
  const int wm = wid >> 1, wn = wid & 1;

  f32x4 acc[4][4] = {};
  const int NT = K >> 5;  // BK = 32

  stage_tile(A, lda, m0, 0, As, wid, lane);
  stage_tile(B, ldb, n0, 0, Bs, wid, lane);
  __syncthreads();

  const int kh = lane >> 4, r16 = lane & 15;
  for (int kt = 0; kt < NT; ++kt) {
    const int cur = kt & 1;
    if (kt + 1 < NT) {
      stage_tile(A, lda, m0, kt + 1, As + (cur ^ 1) * 4096, wid, lane);
      stage_tile(B, ldb, n0, kt + 1, Bs + (cur ^ 1) * 4096, wid, lane);
    }
    const unsigned short* Ab = As + cur * 4096;
    const unsigned short* Bb = Bs + cur * 4096;
    s16x8 af[4], bfr[4];
#pragma unroll
    for (int m = 0; m < 4; ++m)
      af[m] = *(const s16x8*)(Ab + kh * 1024 + (wm * 64 + m * 16 + r16) * 8);
#pragma unroll
    for (int n = 0; n < 4; ++n)
      bfr[n] = *(const s16x8*)(Bb + kh * 1024 + (wn * 64 + n * 16 + r16) * 8);
#pragma unroll
    for (int m = 0; m < 4; ++m)
#pragma unroll
      for (int n = 0; n < 4; ++n)
        acc[m][n] = MFMA_BF16(af[m], bfr[n], acc[m][n]);
    __syncthreads();
  }

  // epilogue: C/D layout col = lane&15, row = (lane>>4)*4 + reg
#pragma unroll
  for (int m = 0; m < 4; ++m) {
    int r = m0 + wm * 64 + m * 16 + (lane >> 4) * 4;
#pragma unroll
    for (int n = 0; n < 4; ++n) {
      int c = n0 + wn * 64 + n * 16 + (lane & 15);
#pragma unroll
      for (int j = 0; j < 4; ++j) {
        float v = acc[m][n][j];
        if (ADD_C) v += Cadd[(size_t)(r + j) * ldadd + c];
        if (OUT_BF16)
          ((unsigned short*)Cp)[(size_t)(r + j) * ldc + c] = f2bf(v);
        else
          ((float*)Cp)[(size_t)(r + j) * ldc + c] = v;
      }
    }
  }
}

template <bool ADD_C, bool OUT_BF16>
__global__ __launch_bounds__(256, 1) void gemm_bt(const unsigned short* __restrict__ A, int lda,
                                                  const unsigned short* __restrict__ B, int ldb,
                                                  void* __restrict__ C, int ldc,
                                                  const float* __restrict__ Cadd, int ldadd,
                                                  int K) {
  __shared__ __align__(16) unsigned short As[2 * 4096];
  __shared__ __align__(16) unsigned short Bs[2 * 4096];
  gemm_core<ADD_C, OUT_BF16>(A, lda, B, ldb, C, ldc, Cadd, ldadd, K,
                             blockIdx.y * 128, blockIdx.x * 128, As, Bs);
}

// Grouped per-expert GEMM over slot slabs (stride 256 rows per expert).
// grid.y = e*2 + row_tile; early-exit when the row tile is beyond this
// expert's token count (outputs there are never read).
template <bool OUT_BF16>
__global__ __launch_bounds__(256, 1) void gemm_grouped(const unsigned short* __restrict__ A0,
                                                       const unsigned short* __restrict__ B0,
                                                       int Bstride, void* __restrict__ C0,
                                                       int N, int K,
                                                       const int* __restrict__ counts) {
  const int e = blockIdx.y >> 1, rt = blockIdx.y & 1;
  int cnt = counts[e];
  if (cnt > 256) cnt = 256;
  if (rt * 128 >= cnt) return;
  __shared__ __align__(16) unsigned short As[2 * 4096];
  __shared__ __align__(16) unsigned short Bs[2 * 4096];
  const int base = e * 256 + rt * 128;
  gemm_core<false, OUT_BF16>(A0 + (size_t)base * K, K, B0 + (size_t)e * Bstride, K,
                             (void*)((unsigned short*)C0 + (size_t)base * (size_t)N * (OUT_BF16 ? 1 : 2)),
                             N, nullptr, 0, K, 0, blockIdx.x * 128, As, Bs);
}

// ---------------------------------------------------------------------------
// f32 -> bf16 conversion of packed segments (+ zero counts in block 0)
// ---------------------------------------------------------------------------
struct ConvSeg { const float* src; unsigned short* dst; };
struct ConvArgs {
  ConvSeg seg[7];
  int blk_end[7];  // cumulative blocks, 4096 elems per block
  int* counts;
};

__global__ void convert_kernel(ConvArgs a) {
  const int b = blockIdx.x, tid = threadIdx.x;
  if (b == 0 && tid < 64) a.counts[tid] = 0;
  int s = 0;
  while (b >= a.blk_end[s]) ++s;
  const int start = s ? a.blk_end[s - 1] : 0;
  const size_t idx = (size_t)(b - start) * 4096 + (size_t)tid * 16;
  unsigned short* dst = a.seg[s].dst + idx;
  const float* src = a.seg[s].src;
  if (src) {
    src += idx;
#pragma unroll
    for (int i = 0; i < 4; ++i) {
      float4 v = *(const float4*)(src + i * 4);
      ushort4 o = make_ushort4(f2bf(v.x), f2bf(v.y), f2bf(v.z), f2bf(v.w));
      *(ushort4*)(dst + i * 4) = o;
    }
  } else {
#pragma unroll
    for (int i = 0; i < 4; ++i) *(ushort4*)(dst + i * 4) = make_ushort4(0, 0, 0, 0);
  }
}

// ---------------------------------------------------------------------------
// Transpose expert weights to B^T layout (bf16):
//   exp_gu_w  [64][256][512] f32 -> egut [64][512][256] bf16
//   exp_down_w[64][256][256] f32 -> edwt [64][256][256] bf16 (transposed)
// 32x32 tiles through LDS.
// ---------------------------------------------------------------------------
__global__ void transpose_kernel(const float* __restrict__ gu, unsigned short* __restrict__ gut,
                                 const float* __restrict__ dw, unsigned short* __restrict__ dwt) {
  const int b = blockIdx.x;
  const float* src; unsigned short* dst; int Cc, tr, tc;
  if (b < 8192) {
    const int e = b >> 7, tt = b & 127;
    tr = tt >> 4; tc = tt & 15;
    src = gu + (size_t)e * 256 * 512; dst = gut + (size_t)e * 512 * 256; Cc = 512;
  } else {
    const int t = b - 8192, e = t >> 6, tt = t & 63;
    tr = tt >> 3; tc = tt & 7;
    src = dw + (size_t)e * 256 * 256; dst = dwt + (size_t)e * 256 * 256; Cc = 256;
  }
  __shared__ float tile[32][33];
  const int tid = threadIdx.x;
  const int r = tid >> 3, c4 = (tid & 7) * 4;
  float4 v = *(const float4*)(src + (size_t)(tr * 32 + r) * Cc + tc * 32 + c4);
  tile[r][c4 + 0] = v.x; tile[r][c4 + 1] = v.y; tile[r][c4 + 2] = v.z; tile[r][c4 + 3] = v.w;
  __syncthreads();
  ushort4 o = make_ushort4(f2bf(tile[c4 + 0][r]), f2bf(tile[c4 + 1][r]),
                           f2bf(tile[c4 + 2][r]), f2bf(tile[c4 + 3][r]));
  *(ushort4*)(dst + (size_t)(tc * 32 + r) * 256 + tr * 32 + c4) = o;
}

// ---------------------------------------------------------------------------
// Router: one wave per token. lane = expert. sigmoid -> top-8 -> gate weights,
// lse^2 for z-loss, atomic slot assignment, gather lat row (bf16) into slabs.
// ---------------------------------------------------------------------------
__global__ void router_kernel(const float* __restrict__ C1, int ldc1,
                              const float* __restrict__ bias,
                              unsigned short* __restrict__ lat_g,
                              int* __restrict__ counts,
                              int* __restrict__ slot_nk, float* __restrict__ gw_nk,
                              float* __restrict__ lse2) {
  const int n = blockIdx.x * 4 + (threadIdx.x >> 6);
  const int lane = threadIdx.x & 63;
  const float* row = C1 + (size_t)n * ldc1;
  const float logit = row[lane];

  // logsumexp
  float mx = logit;
#pragma unroll
  for (int d = 32; d; d >>= 1) mx = fmaxf(mx, __shfl_xor(mx, d));
  float se = expf(logit - mx);
#pragma unroll
  for (int d = 32; d; d >>= 1) se += __shfl_xor(se, d);
  if (lane == 0) {
    const float lse = mx + logf(se);
    lse2[n] = lse * lse;
  }

  const float aff = 1.f / (1.f + expf(-logit));
  float s = aff + bias[lane];

  float asum = 0.f;
  int e_mine = 0; float a_mine = 0.f;
#pragma unroll
  for (int k = 0; k < 8; ++k) {
    float m2 = s;
#pragma unroll
    for (int d = 32; d; d >>= 1) m2 = fmaxf(m2, __shfl_xor(m2, d));
    const unsigned long long blt = __ballot(s == m2);
    const int idx = __ffsll(blt) - 1;        // lowest index on ties (matches top_k)
    const float a = __shfl(aff, idx);
    asum += a;
    if (lane == k) { e_mine = idx; a_mine = a; }
    if (lane == idx) s = -3.0e38f;
  }
  const float inv = 1.f / (asum + 1e-9f);

  int slot = 0;
  if (lane < 8) {
    int pos = atomicAdd(&counts[e_mine], 1);
    if (pos > 255) pos = 255;
    slot = e_mine * 256 + pos;
    slot_nk[(size_t)n * 8 + lane] = slot;
    gw_nk[(size_t)n * 8 + lane] = a_mine * inv;
  }

  // gather this token's latent row (cols 64..320 of C1) into its 8 slots
  const float4 lv = *(const float4*)(row + 64 + lane * 4);
  const ushort4 lb = make_ushort4(f2bf(lv.x), f2bf(lv.y), f2bf(lv.z), f2bf(lv.w));
#pragma unroll
  for (int k = 0; k < 8; ++k) {
    const int sl = __shfl(slot, k);
    *(ushort4*)(lat_g + (size_t)sl * 256 + lane * 4) = lb;
  }
}

__global__ void zreduce_kernel(const float* __restrict__ lse2, float* __restrict__ out) {
  __shared__ float sm[256];
  const int tid = threadIdx.x;
  float s = 0.f;
  for (int i = tid; i < 1024; i += 256) s += lse2[i];
  sm[tid] = s;
  __syncthreads();
  for (int d = 128; d; d >>= 1) {
    if (tid < d) sm[tid] += sm[tid + d];
    __syncthreads();
  }
  if (tid == 0) out[0] = 0.001f * sm[0] / 1024.f;
}

// shared expert SwiGLU: C1 cols [320,1344) = g, [1344,2368) = u
__global__ void swiglu_shared(const float* __restrict__ C1, unsigned short* __restrict__ hid) {
  const int n = blockIdx.x, t = threadIdx.x;
  const float* row = C1 + (size_t)n * 2432 + 320;
  const float4 g = *(const float4*)(row + t * 4);
  const float4 u = *(const float4*)(row + 1024 + t * 4);
  ushort4 o = make_ushort4(f2bf(silu_f(g.x) * u.x), f2bf(silu_f(g.y) * u.y),
                           f2bf(silu_f(g.z) * u.z), f2bf(silu_f(g.w) * u.w));
  *(ushort4*)(hid + (size_t)n * 1024 + t * 4) = o;
}

// expert SwiGLU on slot slabs: h [slot][512] bf16 -> hid [slot][256] bf16
__global__ void swiglu_exp(const unsigned short* __restrict__ h,
                           unsigned short* __restrict__ hid,
                           const int* __restrict__ counts) {
  const int slot = blockIdx.x * 4 + (threadIdx.x >> 6);
  const int lane = threadIdx.x & 63;
  const int e = slot >> 8, pos = slot & 255;
  if (pos >= counts[e]) return;
  const unsigned short* hr = h + (size_t)slot * 512;
  const ushort4 gb = *(const ushort4*)(hr + lane * 4);
  const ushort4 ub = *(const ushort4*)(hr + 256 + lane * 4);
  ushort4 o = make_ushort4(f2bf(silu_f(bf2f(gb.x)) * bf2f(ub.x)),
                           f2bf(silu_f(bf2f(gb.y)) * bf2f(ub.y)),
                           f2bf(silu_f(bf2f(gb.z)) * bf2f(ub.z)),
                           f2bf(silu_f(bf2f(gb.w)) * bf2f(ub.w)));
  *(ushort4*)(hid + (size_t)slot * 256 + lane * 4) = o;
}

// top-8 weighted combine: rl[n][l] = sum_k gw * y[slot][l]; write bf16
__global__ void combine_kernel(const unsigned short* __restrict__ y,
                               const int* __restrict__ slot_nk,
                               const float* __restrict__ gw_nk,
                               unsigned short* __restrict__ rl) {
  const int n = blockIdx.x, l = threadIdx.x;
  float acc = 0.f;
#pragma unroll
  for (int k = 0; k < 8; ++k) {
    const int sl = slot_nk[(size_t)n * 8 + k];
    const float g = gw_nk[(size_t)n * 8 + k];
    acc += g * bf2f(y[(size_t)sl * 256 + l]);
  }
  rl[(size_t)n * 256 + l] = f2bf(acc);
}

// ---------------------------------------------------------------------------
extern "C" void kernel_launch(void* const* d_in, const int* in_sizes, int n_in,
                              void* d_out, int out_size, void* d_ws, size_t ws_size,
                              hipStream_t stream) {
  (void)in_sizes; (void)n_in; (void)out_size; (void)ws_size;
  const float* x      = (const float*)d_in[0];  // [1024,1024]
  const float* gate_w = (const float*)d_in[1];  // [64,1024]
  const float* bias   = (const float*)d_in[2];  // [64]
  const float* down_w = (const float*)d_in[3];  // [256,1024]
  const float* up_w   = (const float*)d_in[4];  // [1024,256]
  const float* sgu    = (const float*)d_in[5];  // [2048,1024]
  const float* sdw    = (const float*)d_in[6];  // [1024,1024]
  const float* egu    = (const float*)d_in[7];  // [64,256,512]
  const float* edw    = (const float*)d_in[8];  // [64,256,256]
  float* out = (float*)d_out;                   // [1024*1024] + z_loss

  char* w = (char*)d_ws;
  auto alloc = [&](size_t bytes) { char* p = w; w += (bytes + 255) & ~(size_t)255; return p; };
  unsigned short* xb    = (unsigned short*)alloc(1048576ull * 2);      // x bf16
  unsigned short* Wcat  = (unsigned short*)alloc(2432ull * 1024 * 2);  // [gate|down|sgu|pad]
  unsigned short* sdwb  = (unsigned short*)alloc(1048576ull * 2);
  unsigned short* upwb  = (unsigned short*)alloc(262144ull * 2);
  unsigned short* egut  = (unsigned short*)alloc(64ull * 512 * 256 * 2);
  unsigned short* edwt  = (unsigned short*)alloc(64ull * 256 * 256 * 2);
  float*          C1    = (float*)alloc(1024ull * 2432 * 4);           // logits|lat|sh
  unsigned short* hidsh = (unsigned short*)alloc(1048576ull * 2);
  float*          shout = (float*)alloc(1048576ull * 4);
  unsigned short* lat_g = (unsigned short*)alloc(16384ull * 256 * 2);
  unsigned short* hbuf  = (unsigned short*)alloc(16384ull * 512 * 2);
  unsigned short* hide  = (unsigned short*)alloc(16384ull * 256 * 2);
  unsigned short* ybuf  = (unsigned short*)alloc(16384ull * 256 * 2);
  unsigned short* rlbf  = (unsigned short*)alloc(262144ull * 2);
  int*   counts  = (int*)alloc(64 * 4);
  int*   slot_nk = (int*)alloc(8192 * 4);
  float* gw_nk   = (float*)alloc(8192 * 4);
  float* lse2    = (float*)alloc(1024 * 4);

  // 1. convert + pack (and zero counts)
  ConvArgs ca;
  ca.seg[0] = { x,      xb };                 // 1048576
  ca.seg[1] = { gate_w, Wcat };               // 65536   (rows 0..63)
  ca.seg[2] = { down_w, Wcat + 65536 };       // 262144  (rows 64..319)
  ca.seg[3] = { sgu,    Wcat + 327680 };      // 2097152 (rows 320..2367)
  ca.seg[4] = { nullptr, Wcat + 2424832 };    // 65536   (pad rows -> zero)
  ca.seg[5] = { sdw,    sdwb };               // 1048576
  ca.seg[6] = { up_w,   upwb };               // 262144
  ca.blk_end[0] = 256;  ca.blk_end[1] = 272;  ca.blk_end[2] = 336;
  ca.blk_end[3] = 848;  ca.blk_end[4] = 864;  ca.blk_end[5] = 1120;
  ca.blk_end[6] = 1184;
  ca.counts = counts;
  convert_kernel<<<dim3(1184), dim3(256), 0, stream>>>(ca);

  // 2. transpose expert weights to B^T bf16
  transpose_kernel<<<dim3(12288), dim3(256), 0, stream>>>(egu, egut, edw, edwt);

  // 3. fused GEMM: [logits | lat | shared gu] = xb @ Wcat^T  (M=1024,N=2432,K=1024)
  gemm_bt<false, false><<<dim3(19, 8), dim3(256), 0, stream>>>(
      xb, 1024, Wcat, 1024, (void*)C1, 2432, nullptr, 0, 1024);

  // 4. router: top-8, gates, lse2, slot scatter + lat gather
  router_kernel<<<dim3(256), dim3(256), 0, stream>>>(
      C1, 2432, bias, lat_g, counts, slot_nk, gw_nk, lse2);

  // 5. z-loss
  zreduce_kernel<<<dim3(1), dim3(256), 0, stream>>>(lse2, out + 1048576);

  // 6. shared SwiGLU
  swiglu_shared<<<dim3(1024), dim3(256), 0, stream>>>(C1, hidsh);

  // 7. shared down GEMM -> shout
  gemm_bt<false, false><<<dim3(8, 8), dim3(256), 0, stream>>>(
      hidsh, 1024, sdwb, 1024, (void*)shout, 1024, nullptr, 0, 1024);

  // 8. grouped expert GU GEMM: h = lat_g @ egut^T (per expert), bf16 out
  gemm_grouped<true><<<dim3(4, 128), dim3(256), 0, stream>>>(
      lat_g, egut, 512 * 256, (void*)hbuf, 512, 256, counts);

  // 9. expert SwiGLU
  swiglu_exp<<<dim3(4096), dim3(256), 0, stream>>>(hbuf, hide, counts);

  // 10. grouped expert down GEMM: y = hide @ edwt^T, bf16 out
  gemm_grouped<true><<<dim3(2, 128), dim3(256), 0, stream>>>(
      hide, edwt, 256 * 256, (void*)ybuf, 256, 256, counts);

  // 11. combine top-8
  combine_kernel<<<dim3(1024), dim3(256), 0, stream>>>(ybuf, slot_nk, gw_nk, rlbf);

  // 12. final up GEMM + shared_out -> d_out
  gemm_bt<true, false><<<dim3(8, 8), dim3(256), 0, stream>>>(
      rlbf, 256, upwb, 256, (void*)out, 1024, shout, 1024, 256);
}

// Round 2
// 158.878 us; speedup vs baseline: 1.0361x; 1.0361x over previous
//
#include <hip/hip_runtime.h>
#include <stdint.h>

// ---------------------------------------------------------------------------
// LatentMoE forward, MI355X (gfx950). bf16 MFMA, f32 accumulate. 7 dispatches:
//  1. pack    : f32->bf16 convert + weight packing/transposes (+zero counts,z)
//  2. gemm1   : [logits|lat] f32 + fused-SwiGLU shared hidden -> Abuf[:,0:1024]
//  3. router  : sigmoid/top-8/gates + z-loss atomic + latent slab gather
//  4. gemmGU  : grouped expert gate/up GEMM + fused SwiGLU -> hide
//  5. gemmDW  : grouped expert down GEMM -> ybuf
//  6. combine : top-8 weighted sum -> Abuf[:,1024:1280]
//  7. gemmF   : [hid|rl] @ [sdw|up]^T  (K=1280) -> out
// ---------------------------------------------------------------------------

using f32x4 = __attribute__((ext_vector_type(4))) float;
using s16x8 = __attribute__((ext_vector_type(8))) short;

#define MFMA_BF16(a, b, c) __builtin_amdgcn_mfma_f32_16x16x32_bf16((a), (b), (c), 0, 0, 0)

__device__ __forceinline__ unsigned short f2bf(float f) {
  union { float f; uint32_t u; } v; v.f = f;
  uint32_t u = v.u;
  u += 0x7FFFu + ((u >> 16) & 1u);
  return (unsigned short)(u >> 16);
}
__device__ __forceinline__ float bf2f(unsigned short h) {
  union { uint32_t u; float f; } v; v.u = ((uint32_t)h) << 16;
  return v.f;
}
__device__ __forceinline__ float silu_f(float x) { return x / (1.f + expf(-x)); }

__device__ __forceinline__ void cvt16(const float* __restrict__ src,
                                      unsigned short* __restrict__ dst) {
  if (src) {
#pragma unroll
    for (int i = 0; i < 4; ++i) {
      float4 v = *(const float4*)(src + i * 4);
      *(ushort4*)(dst + i * 4) =
          make_ushort4(f2bf(v.x), f2bf(v.y), f2bf(v.z), f2bf(v.w));
    }
  } else {
#pragma unroll
    for (int i = 0; i < 4; ++i) *(ushort4*)(dst + i * 4) = make_ushort4(0, 0, 0, 0);
  }
}

// ---------------------------------------------------------------------------
// Pack kernel: all f32->bf16 conversion, packing, and transposes in 1 launch.
//  blocks [0,608)      : Wcat [2432][1024]  (gate | down | pad | sgu g/u-interleaved)
//  blocks [608,928)    : Bf   [1024][1280]  (sdw | up_w)
//  blocks [928,1184)   : xb   [1024][1024]
//  blocks [1184,9376)  : egut [64][512][256] (transpose + g/u interleave)
//  blocks [9376,13472) : edwt [64][256][256] (transpose)
// ---------------------------------------------------------------------------
struct PackArgs {
  const float *x, *gate, *down, *sgu, *sdw, *up, *egu, *edw;
  unsigned short *xb, *Wcat, *Bf, *egut, *edwt;
  int* counts;
  float* zp;
};

__global__ void pack_kernel(PackArgs a) {
  __shared__ float tile[32][33];
  const int b = blockIdx.x, t = threadIdx.x;
  if (b == 0) {
    if (t < 64) a.counts[t] = 0;
    if (t == 64) *a.zp = 0.f;
  }
  if (b < 608) {
    const int r = b * 4 + (t >> 6), c = (t & 63) * 16;
    const float* src;
    if (r < 64)       src = a.gate + (size_t)r * 1024 + c;
    else if (r < 320) src = a.down + (size_t)(r - 64) * 1024 + c;
    else if (r < 384) src = nullptr;                         // pad rows -> 0
    else {
      const int i = r - 384;                                  // g/u interleave
      src = a.sgu + (size_t)((i >> 1) + (i & 1) * 1024) * 1024 + c;
    }
    cvt16(src, a.Wcat + (size_t)r * 1024 + c);
  } else if (b < 928) {
    const int idx = (b - 608) * 4096 + t * 16;
    const int row = idx / 1280, col = idx - row * 1280;
    const float* src = (col < 1024) ? a.sdw + (size_t)row * 1024 + col
                                    : a.up + (size_t)row * 256 + (col - 1024);
    cvt16(src, a.Bf + idx);
  } else if (b < 1184) {
    const int idx = (b - 928) * 4096 + t * 16;
    cvt16(a.x + idx, a.xb + idx);
  } else {
    // transpose branch: 32x32 f32 tiles through LDS
    const float* src; unsigned short* dst; int lds, tr, tc; bool inter;
    if (b < 9376) {
      const int q = b - 1184, e = q >> 7, tt = q & 127;
      tr = tt >> 4; tc = tt & 15; lds = 512; inter = true;
      src = a.egu + (size_t)e * 131072; dst = a.egut + (size_t)e * 131072;
    } else {
      const int q = b - 9376, e = q >> 6, tt = q & 63;
      tr = tt >> 3; tc = tt & 7; lds = 256; inter = false;
      src = a.edw + (size_t)e * 65536; dst = a.edwt + (size_t)e * 65536;
    }
    const int r = t >> 3, c4 = (t & 7) * 4;
    float4 v = *(const float4*)(src + (size_t)(tr * 32 + r) * lds + tc * 32 + c4);
    tile[r][c4 + 0] = v.x; tile[r][c4 + 1] = v.y;
    tile[r][c4 + 2] = v.z; tile[r][c4 + 3] = v.w;
    __syncthreads();
    const int n = tc * 32 + r;                               // source col = out row
    const int orow = inter ? ((n < 256) ? 2 * n : 2 * (n - 256) + 1) : n;
    ushort4 o = make_ushort4(f2bf(tile[c4 + 0][r]), f2bf(tile[c4 + 1][r]),
                             f2bf(tile[c4 + 2][r]), f2bf(tile[c4 + 3][r]));
    *(ushort4*)(dst + (size_t)orow * 256 + tr * 32 + c4) = o;
  }
}

// ---------------------------------------------------------------------------
// GEMM core, 128x128 tile, 4 waves (2x2), 16x16x32 bf16 MFMA, 2-stage LDS dbuf
// via global_load_lds(16B). Epilogue modes: 0=f32 store, 1=bf16 store,
// 2=fused SwiGLU (g/u in adjacent lanes, shfl_xor(1), even lanes store bf16).
// ---------------------------------------------------------------------------
struct EpiArgs { int mode; void* out; int ldo; int coff; };

__device__ __forceinline__ void stage_tile(const unsigned short* __restrict__ G, int ldg,
                                           int row0, int kt, unsigned short* lbuf,
                                           int wid, int lane) {
#pragma unroll
  for (int j = 0; j < 2; ++j) {
    const int o = j * 4096 + wid * 1024 + lane * 16;  // byte offset in 8KB tile
    const int kh = o >> 11;                           // 0..3
    const int row = (o & 2047) >> 4;                  // 0..127
    const unsigned short* src = G + (size_t)(row0 + row) * ldg + kt * 32 + kh * 8;
    __builtin_amdgcn_global_load_lds(
        (const __attribute__((address_space(1))) void*)src,
        (__attribute__((address_space(3))) void*)(lbuf + (size_t)(j * 2048 + wid * 512)),
        16, 0, 0);
  }
}

__device__ __forceinline__ void gemm_tile(const unsigned short* __restrict__ A, int lda,
                                          const unsigned short* __restrict__ B, int ldb,
                                          int K, int m0, int n0, EpiArgs epi,
                                          unsigned short* As, unsigned short* Bs) {
  const int tid = threadIdx.x;
  const int wid = tid >> 6, lane = tid & 63;
  const int wm = wid >> 1, wn = wid & 1;

  f32x4 acc[4][4] = {};
  const int NT = K >> 5;

  stage_tile(A, lda, m0, 0, As, wid, lane);
  stage_tile(B, ldb, n0, 0, Bs, wid, lane);
  __syncthreads();

  const int kh = lane >> 4, r16 = lane & 15;
  for (int kt = 0; kt < NT; ++kt) {
    const int cur = kt & 1;
    if (kt + 1 < NT) {
      stage_tile(A, lda, m0, kt + 1, As + (cur ^ 1) * 4096, wid, lane);
      stage_tile(B, ldb, n0, kt + 1, Bs + (cur ^ 1) * 4096, wid, lane);
    }
    const unsigned short* Ab = As + cur * 4096;
    const unsigned short* Bb = Bs + cur * 4096;
    s16x8 af[4], bfr[4];
#pragma unroll
    for (int m = 0; m < 4; ++m)
      af[m] = *(const s16x8*)(Ab + kh * 1024 + (wm * 64 + m * 16 + r16) * 8);
#pragma unroll
    for (int n = 0; n < 4; ++n)
      bfr[n] = *(const s16x8*)(Bb + kh * 1024 + (wn * 64 + n * 16 + r16) * 8);
#pragma unroll
    for (int m = 0; m < 4; ++m)
#pragma unroll
      for (int n = 0; n < 4; ++n)
        acc[m][n] = MFMA_BF16(af[m], bfr[n], acc[m][n]);
    __syncthreads();
  }

  // epilogue: C/D layout col = lane&15, row = (lane>>4)*4 + reg
#pragma unroll
  for (int m = 0; m < 4; ++m) {
    const int rb = m0 + wm * 64 + m * 16 + (lane >> 4) * 4;
#pragma unroll
    for (int n = 0; n < 4; ++n) {
      const int c = n0 + wn * 64 + n * 16 + (lane & 15);
      if (epi.mode == 0) {
        float* O = (float*)epi.out;
#pragma unroll
        for (int j = 0; j < 4; ++j) O[(size_t)(rb + j) * epi.ldo + c] = acc[m][n][j];
      } else if (epi.mode == 1) {
        unsigned short* O = (unsigned short*)epi.out;
#pragma unroll
        for (int j = 0; j < 4; ++j)
          O[(size_t)(rb + j) * epi.ldo + c] = f2bf(acc[m][n][j]);
      } else {
        unsigned short* O = (unsigned short*)epi.out;
        const int col = (c - epi.coff) >> 1;
#pragma unroll
        for (int j = 0; j < 4; ++j) {
          const float v = acc[m][n][j];
          const float u = __shfl_xor(v, 1);
          if (!(lane & 1))
            O[(size_t)(rb + j) * epi.ldo + col] = f2bf(silu_f(v) * u);
        }
      }
    }
  }
}

// GEMM1: [logits|lat] -> C1 f32 (tiles 0..2); fused shared SwiGLU -> Abuf (3..18)
__global__ __launch_bounds__(256, 1) void gemm1_kernel(const unsigned short* __restrict__ xb,
                                                       const unsigned short* __restrict__ Wcat,
                                                       float* __restrict__ C1,
                                                       unsigned short* __restrict__ Abuf) {
  __shared__ __align__(16) unsigned short As[2 * 4096];
  __shared__ __align__(16) unsigned short Bs[2 * 4096];
  const int bx = blockIdx.x;
  EpiArgs e;
  if (bx < 3) { e.mode = 0; e.out = C1; e.ldo = 384; e.coff = 0; }
  else        { e.mode = 2; e.out = Abuf; e.ldo = 1280; e.coff = 384; }
  gemm_tile(xb, 1024, Wcat, 1024, 1024, blockIdx.y * 128, bx * 128, e, As, Bs);
}

// final: out = [hid|rl] @ [sdw|up]^T, K=1280
__global__ __launch_bounds__(256, 1) void gemm_final(const unsigned short* __restrict__ Abuf,
                                                     const unsigned short* __restrict__ Bf,
                                                     float* __restrict__ out) {
  __shared__ __align__(16) unsigned short As[2 * 4096];
  __shared__ __align__(16) unsigned short Bs[2 * 4096];
  EpiArgs e; e.mode = 0; e.out = out; e.ldo = 1024; e.coff = 0;
  gemm_tile(Abuf, 1280, Bf, 1280, 1280, blockIdx.y * 128, blockIdx.x * 128, e, As, Bs);
}

// grouped per-expert GEMM over slot slabs (256 slots/expert, K=256)
__global__ __launch_bounds__(256, 1) void gemm_grouped(const unsigned short* __restrict__ A0,
                                                       const unsigned short* __restrict__ B0,
                                                       int Bstride, EpiArgs epi, int K,
                                                       const int* __restrict__ counts) {
  const int e = blockIdx.y >> 1, rt = blockIdx.y & 1;
  int cnt = counts[e];
  if (cnt > 256) cnt = 256;
  if (rt * 128 >= cnt) return;
  __shared__ __align__(16) unsigned short As[2 * 4096];
  __shared__ __align__(16) unsigned short Bs[2 * 4096];
  const int base = e * 256 + rt * 128;
  epi.out = (void*)((unsigned short*)epi.out + (size_t)base * epi.ldo);
  gemm_tile(A0 + (size_t)base * K, K, B0 + (size_t)e * Bstride, K, K, 0,
            blockIdx.x * 128, epi, As, Bs);
}

// ---------------------------------------------------------------------------
// Router: one wave per token; sigmoid, top-8, gates, z-loss atomic, lat gather.
// ---------------------------------------------------------------------------
__global__ void router_kernel(const float* __restrict__ C1,
                              const float* __restrict__ bias,
                              unsigned short* __restrict__ lat_g,
                              int* __restrict__ counts,
                              int* __restrict__ slot_nk, float* __restrict__ gw_nk,
                              float* __restrict__ zp) {
  const int n = blockIdx.x * 4 + (threadIdx.x >> 6);
  const int lane = threadIdx.x & 63;
  const float* row = C1 + (size_t)n * 384;
  const float logit = row[lane];

  float mx = logit;
#pragma unroll
  for (int d = 32; d; d >>= 1) mx = fmaxf(mx, __shfl_xor(mx, d));
  float se = expf(logit - mx);
#pragma unroll
  for (int d = 32; d; d >>= 1) se += __shfl_xor(se, d);
  if (lane == 0) {
    const float lse = mx + logf(se);
    atomicAdd(zp, 0.001f * lse * lse * (1.f / 1024.f));
  }

  const float aff = 1.f / (1.f + expf(-logit));
  float s = aff + bias[lane];

  float asum = 0.f;
  int e_mine = 0; float a_mine = 0.f;
#pragma unroll
  for (int k = 0; k < 8; ++k) {
    float m2 = s;
#pragma unroll
    for (int d = 32; d; d >>= 1) m2 = fmaxf(m2, __shfl_xor(m2, d));
    const unsigned long long blt = __ballot(s == m2);
    const int idx = __ffsll(blt) - 1;  // lowest index on ties (matches top_k)
    const float a = __shfl(aff, idx);
    asum += a;
    if (lane == k) { e_mine = idx; a_mine = a; }
    if (lane == idx) s = -3.0e38f;
  }
  const float inv = 1.f / (asum + 1e-9f);

  int slot = 0;
  if (lane < 8) {
    int pos = atomicAdd(&counts[e_mine], 1);
    if (pos > 255) pos = 255;
    slot = e_mine * 256 + pos;
    slot_nk[(size_t)n * 8 + lane] = slot;
    gw_nk[(size_t)n * 8 + lane] = a_mine * inv;
  }

  const float4 lv = *(const float4*)(row + 64 + lane * 4);
  const ushort4 lb = make_ushort4(f2bf(lv.x), f2bf(lv.y), f2bf(lv.z), f2bf(lv.w));
#pragma unroll
  for (int k = 0; k < 8; ++k) {
    const int sl = __shfl(slot, k);
    *(ushort4*)(lat_g + (size_t)sl * 256 + lane * 4) = lb;
  }
}

// top-8 weighted combine -> Abuf cols [1024,1280)
__global__ void combine_kernel(const unsigned short* __restrict__ y,
                               const int* __restrict__ slot_nk,
                               const float* __restrict__ gw_nk,
                               unsigned short* __restrict__ Abuf) {
  const int n = blockIdx.x * 4 + (threadIdx.x >> 6);
  const int l4 = (threadIdx.x & 63) * 4;
  float a0 = 0.f, a1 = 0.f, a2 = 0.f, a3 = 0.f;
#pragma unroll
  for (int k = 0; k < 8; ++k) {
    const int sl = slot_nk[(size_t)n * 8 + k];
    const float g = gw_nk[(size_t)n * 8 + k];
    const ushort4 yv = *(const ushort4*)(y + (size_t)sl * 256 + l4);
    a0 += g * bf2f(yv.x); a1 += g * bf2f(yv.y);
    a2 += g * bf2f(yv.z); a3 += g * bf2f(yv.w);
  }
  *(ushort4*)(Abuf + (size_t)n * 1280 + 1024 + l4) =
      make_ushort4(f2bf(a0), f2bf(a1), f2bf(a2), f2bf(a3));
}

// ---------------------------------------------------------------------------
extern "C" void kernel_launch(void* const* d_in, const int* in_sizes, int n_in,
                              void* d_out, int out_size, void* d_ws, size_t ws_size,
                              hipStream_t stream) {
  (void)in_sizes; (void)n_in; (void)out_size; (void)ws_size;
  const float* x      = (const float*)d_in[0];
  const float* gate_w = (const float*)d_in[1];
  const float* bias   = (const float*)d_in[2];
  const float* down_w = (const float*)d_in[3];
  const float* up_w   = (const float*)d_in[4];
  const float* sgu    = (const float*)d_in[5];
  const float* sdw    = (const float*)d_in[6];
  const float* egu    = (const float*)d_in[7];
  const float* edw    = (const float*)d_in[8];
  float* out = (float*)d_out;  // [1024*1024] + z_loss

  char* w = (char*)d_ws;
  auto alloc = [&](size_t bytes) { char* p = w; w += (bytes + 255) & ~(size_t)255; return p; };
  unsigned short* xb    = (unsigned short*)alloc(1048576ull * 2);
  unsigned short* Wcat  = (unsigned short*)alloc(2432ull * 1024 * 2);
  unsigned short* Bf    = (unsigned short*)alloc(1024ull * 1280 * 2);
  unsigned short* egut  = (unsigned short*)alloc(64ull * 512 * 256 * 2);
  unsigned short* edwt  = (unsigned short*)alloc(64ull * 256 * 256 * 2);
  float*          C1    = (float*)alloc(1024ull * 384 * 4);
  unsigned short* Abuf  = (unsigned short*)alloc(1024ull * 1280 * 2);
  unsigned short* lat_g = (unsigned short*)alloc(16384ull * 256 * 2);
  unsigned short* hide  = (unsigned short*)alloc(16384ull * 256 * 2);
  unsigned short* ybuf  = (unsigned short*)alloc(16384ull * 256 * 2);
  int*   counts  = (int*)alloc(64 * 4);
  int*   slot_nk = (int*)alloc(8192 * 4);
  float* gw_nk   = (float*)alloc(8192 * 4);

  // 1. pack everything (+ zero counts and z slot)
  PackArgs pa;
  pa.x = x; pa.gate = gate_w; pa.down = down_w; pa.sgu = sgu; pa.sdw = sdw;
  pa.up = up_w; pa.egu = egu; pa.edw = edw;
  pa.xb = xb; pa.Wcat = Wcat; pa.Bf = Bf; pa.egut = egut; pa.edwt = edwt;
  pa.counts = counts; pa.zp = out + 1048576;
  pack_kernel<<<dim3(13472), dim3(256), 0, stream>>>(pa);

  // 2. gemm1: logits|lat (f32) + fused shared SwiGLU -> Abuf[:,0:1024]
  gemm1_kernel<<<dim3(19, 8), dim3(256), 0, stream>>>(xb, Wcat, C1, Abuf);

  // 3. router
  router_kernel<<<dim3(256), dim3(256), 0, stream>>>(
      C1, bias, lat_g, counts, slot_nk, gw_nk, out + 1048576);

  // 4. grouped GU GEMM + fused SwiGLU -> hide
  {
    EpiArgs e; e.mode = 2; e.out = hide; e.ldo = 256; e.coff = 0;
    gemm_grouped<<<dim3(4, 128), dim3(256), 0, stream>>>(
        lat_g, egut, 512 * 256, e, 256, counts);
  }

  // 5. grouped down GEMM -> ybuf
  {
    EpiArgs e; e.mode = 1; e.out = ybuf; e.ldo = 256; e.coff = 0;
    gemm_grouped<<<dim3(2, 128), dim3(256), 0, stream>>>(
        hide, edwt, 256 * 256, e, 256, counts);
  }

  // 6. combine -> Abuf[:,1024:1280)
  combine_kernel<<<dim3(256), dim3(256), 0, stream>>>(ybuf, slot_nk, gw_nk, Abuf);

  // 7. final fused GEMM (shared-down + routed-up in one K=1280 pass)
  gemm_final<<<dim3(8, 8), dim3(256), 0, stream>>>(Abuf, Bf, out);
}

// Round 3
// 140.051 us; speedup vs baseline: 1.1754x; 1.1344x over previous
//
#include <hip/hip_runtime.h>
#include <stdint.h>

// ---------------------------------------------------------------------------
// LatentMoE forward, MI355X (gfx950). bf16 MFMA, f32 accumulate. 7 dispatches.
// R3: GEMM core now triple-buffered with counted s_waitcnt vmcnt(N) + raw
// s_barrier (no vmcnt(0) drain per K-step) -> hides L2/L3 latency at 1 blk/CU.
// ---------------------------------------------------------------------------

using f32x4 = __attribute__((ext_vector_type(4))) float;
using s16x8 = __attribute__((ext_vector_type(8))) short;

#define MFMA_BF16(a, b, c) __builtin_amdgcn_mfma_f32_16x16x32_bf16((a), (b), (c), 0, 0, 0)

__device__ __forceinline__ unsigned short f2bf(float f) {
  union { float f; uint32_t u; } v; v.f = f;
  uint32_t u = v.u;
  u += 0x7FFFu + ((u >> 16) & 1u);
  return (unsigned short)(u >> 16);
}
__device__ __forceinline__ float bf2f(unsigned short h) {
  union { uint32_t u; float f; } v; v.u = ((uint32_t)h) << 16;
  return v.f;
}
__device__ __forceinline__ float silu_f(float x) { return x / (1.f + expf(-x)); }

__device__ __forceinline__ void cvt16(const float* __restrict__ src,
                                      unsigned short* __restrict__ dst) {
  if (src) {
#pragma unroll
    for (int i = 0; i < 4; ++i) {
      float4 v = *(const float4*)(src + i * 4);
      *(ushort4*)(dst + i * 4) =
          make_ushort4(f2bf(v.x), f2bf(v.y), f2bf(v.z), f2bf(v.w));
    }
  } else {
#pragma unroll
    for (int i = 0; i < 4; ++i) *(ushort4*)(dst + i * 4) = make_ushort4(0, 0, 0, 0);
  }
}

// ---------------------------------------------------------------------------
// Pack kernel (unchanged from R2)
// ---------------------------------------------------------------------------
struct PackArgs {
  const float *x, *gate, *down, *sgu, *sdw, *up, *egu, *edw;
  unsigned short *xb, *Wcat, *Bf, *egut, *edwt;
  int* counts;
  float* zp;
};

__global__ void pack_kernel(PackArgs a) {
  __shared__ float tile[32][33];
  const int b = blockIdx.x, t = threadIdx.x;
  if (b == 0) {
    if (t < 64) a.counts[t] = 0;
    if (t == 64) *a.zp = 0.f;
  }
  if (b < 608) {
    const int r = b * 4 + (t >> 6), c = (t & 63) * 16;
    const float* src;
    if (r < 64)       src = a.gate + (size_t)r * 1024 + c;
    else if (r < 320) src = a.down + (size_t)(r - 64) * 1024 + c;
    else if (r < 384) src = nullptr;
    else {
      const int i = r - 384;
      src = a.sgu + (size_t)((i >> 1) + (i & 1) * 1024) * 1024 + c;
    }
    cvt16(src, a.Wcat + (size_t)r * 1024 + c);
  } else if (b < 928) {
    const int idx = (b - 608) * 4096 + t * 16;
    const int row = idx / 1280, col = idx - row * 1280;
    const float* src = (col < 1024) ? a.sdw + (size_t)row * 1024 + col
                                    : a.up + (size_t)row * 256 + (col - 1024);
    cvt16(src, a.Bf + idx);
  } else if (b < 1184) {
    const int idx = (b - 928) * 4096 + t * 16;
    cvt16(a.x + idx, a.xb + idx);
  } else {
    const float* src; unsigned short* dst; int lds, tr, tc; bool inter;
    if (b < 9376) {
      const int q = b - 1184, e = q >> 7, tt = q & 127;
      tr = tt >> 4; tc = tt & 15; lds = 512; inter = true;
      src = a.egu + (size_t)e * 131072; dst = a.egut + (size_t)e * 131072;
    } else {
      const int q = b - 9376, e = q >> 6, tt = q & 63;
      tr = tt >> 3; tc = tt & 7; lds = 256; inter = false;
      src = a.edw + (size_t)e * 65536; dst = a.edwt + (size_t)e * 65536;
    }
    const int r = t >> 3, c4 = (t & 7) * 4;
    float4 v = *(const float4*)(src + (size_t)(tr * 32 + r) * lds + tc * 32 + c4);
    tile[r][c4 + 0] = v.x; tile[r][c4 + 1] = v.y;
    tile[r][c4 + 2] = v.z; tile[r][c4 + 3] = v.w;
    __syncthreads();
    const int n = tc * 32 + r;
    const int orow = inter ? ((n < 256) ? 2 * n : 2 * (n - 256) + 1) : n;
    ushort4 o = make_ushort4(f2bf(tile[c4 + 0][r]), f2bf(tile[c4 + 1][r]),
                             f2bf(tile[c4 + 2][r]), f2bf(tile[c4 + 3][r]));
    *(ushort4*)(dst + (size_t)orow * 256 + tr * 32 + c4) = o;
  }
}

// ---------------------------------------------------------------------------
// GEMM core, 128x128 tile, 4 waves (2x2), 16x16x32 bf16 MFMA.
// Triple-buffered LDS pipeline, counted vmcnt, raw s_barrier (1 per K-step).
// ---------------------------------------------------------------------------
struct EpiArgs { int mode; void* out; int ldo; int coff; };

__device__ __forceinline__ void stage_tile(const unsigned short* __restrict__ G, int ldg,
                                           int row0, int kt, unsigned short* lbuf,
                                           int wid, int lane) {
#pragma unroll
  for (int j = 0; j < 2; ++j) {
    const int o = j * 4096 + wid * 1024 + lane * 16;  // byte offset in 8KB tile
    const int kh = o >> 11;                           // 0..3
    const int row = (o & 2047) >> 4;                  // 0..127
    const unsigned short* src = G + (size_t)(row0 + row) * ldg + kt * 32 + kh * 8;
    __builtin_amdgcn_global_load_lds(
        (const __attribute__((address_space(1))) void*)src,
        (__attribute__((address_space(3))) void*)(lbuf + (size_t)(j * 2048 + wid * 512)),
        16, 0, 0);
  }
}

__device__ __forceinline__ void wave_fence() { asm volatile("" ::: "memory"); }

__device__ __forceinline__ void gemm_tile(const unsigned short* __restrict__ A, int lda,
                                          const unsigned short* __restrict__ B, int ldb,
                                          int K, int m0, int n0, EpiArgs epi,
                                          unsigned short* As, unsigned short* Bs) {
  const int tid = threadIdx.x;
  const int wid = tid >> 6, lane = tid & 63;
  const int wm = wid >> 1, wn = wid & 1;

  f32x4 acc[4][4] = {};
  const int NT = K >> 5;  // BK = 32

  // prologue: stage tiles 0 and 1 (each wave: 4 loads per tile)
  stage_tile(A, lda, m0, 0, As, wid, lane);
  stage_tile(B, ldb, n0, 0, Bs, wid, lane);
  if (NT > 1) {
    stage_tile(A, lda, m0, 1, As + 4096, wid, lane);
    stage_tile(B, ldb, n0, 1, Bs + 4096, wid, lane);
  }

  const int kh = lane >> 4, r16 = lane & 15;
  int cur = 0;
  for (int kt = 0; kt < NT; ++kt) {
    // wait for OWN tile-kt loads only (oldest 4); keep kt+1 (and kt+2) in flight
    if (kt + 1 < NT) asm volatile("s_waitcnt vmcnt(4)" ::: "memory");
    else             asm volatile("s_waitcnt vmcnt(0)" ::: "memory");
    wave_fence();
    __builtin_amdgcn_s_barrier();   // now tile kt fully in LDS; prev reads done
    wave_fence();

    const unsigned short* Ab = As + cur * 4096;
    const unsigned short* Bb = Bs + cur * 4096;
    s16x8 af[4], bfr[4];
#pragma unroll
    for (int m = 0; m < 4; ++m)
      af[m] = *(const s16x8*)(Ab + kh * 1024 + (wm * 64 + m * 16 + r16) * 8);
#pragma unroll
    for (int n = 0; n < 4; ++n)
      bfr[n] = *(const s16x8*)(Bb + kh * 1024 + (wn * 64 + n * 16 + r16) * 8);

    if (kt + 2 < NT) {  // stage tile kt+2 into the buffer last read at iter kt-1
      const int nb = (cur + 2 >= 3) ? cur - 1 : cur + 2;
      stage_tile(A, lda, m0, kt + 2, As + nb * 4096, wid, lane);
      stage_tile(B, ldb, n0, kt + 2, Bs + nb * 4096, wid, lane);
    }

    __builtin_amdgcn_s_setprio(1);
#pragma unroll
    for (int m = 0; m < 4; ++m)
#pragma unroll
      for (int n = 0; n < 4; ++n)
        acc[m][n] = MFMA_BF16(af[m], bfr[n], acc[m][n]);
    __builtin_amdgcn_s_setprio(0);

    cur = (cur + 1 == 3) ? 0 : cur + 1;
  }

  // epilogue: C/D layout col = lane&15, row = (lane>>4)*4 + reg
#pragma unroll
  for (int m = 0; m < 4; ++m) {
    const int rb = m0 + wm * 64 + m * 16 + (lane >> 4) * 4;
#pragma unroll
    for (int n = 0; n < 4; ++n) {
      const int c = n0 + wn * 64 + n * 16 + (lane & 15);
      if (epi.mode == 0) {
        float* O = (float*)epi.out;
#pragma unroll
        for (int j = 0; j < 4; ++j) O[(size_t)(rb + j) * epi.ldo + c] = acc[m][n][j];
      } else if (epi.mode == 1) {
        unsigned short* O = (unsigned short*)epi.out;
#pragma unroll
        for (int j = 0; j < 4; ++j)
          O[(size_t)(rb + j) * epi.ldo + c] = f2bf(acc[m][n][j]);
      } else {
        unsigned short* O = (unsigned short*)epi.out;
        const int col = (c - epi.coff) >> 1;
#pragma unroll
        for (int j = 0; j < 4; ++j) {
          const float v = acc[m][n][j];
          const float u = __shfl_xor(v, 1);
          if (!(lane & 1))
            O[(size_t)(rb + j) * epi.ldo + col] = f2bf(silu_f(v) * u);
        }
      }
    }
  }
}

// GEMM1: [logits|lat] -> C1 f32 (tiles 0..2); fused shared SwiGLU -> Abuf (3..18)
__global__ __launch_bounds__(256, 1) void gemm1_kernel(const unsigned short* __restrict__ xb,
                                                       const unsigned short* __restrict__ Wcat,
                                                       float* __restrict__ C1,
                                                       unsigned short* __restrict__ Abuf) {
  __shared__ __align__(16) unsigned short As[3 * 4096];
  __shared__ __align__(16) unsigned short Bs[3 * 4096];
  const int bx = blockIdx.x;
  EpiArgs e;
  if (bx < 3) { e.mode = 0; e.out = C1; e.ldo = 384; e.coff = 0; }
  else        { e.mode = 2; e.out = Abuf; e.ldo = 1280; e.coff = 384; }
  gemm_tile(xb, 1024, Wcat, 1024, 1024, blockIdx.y * 128, bx * 128, e, As, Bs);
}

// final: out = [hid|rl] @ [sdw|up]^T, K=1280
__global__ __launch_bounds__(256, 1) void gemm_final(const unsigned short* __restrict__ Abuf,
                                                     const unsigned short* __restrict__ Bf,
                                                     float* __restrict__ out) {
  __shared__ __align__(16) unsigned short As[3 * 4096];
  __shared__ __align__(16) unsigned short Bs[3 * 4096];
  EpiArgs e; e.mode = 0; e.out = out; e.ldo = 1024; e.coff = 0;
  gemm_tile(Abuf, 1280, Bf, 1280, 1280, blockIdx.y * 128, blockIdx.x * 128, e, As, Bs);
}

// grouped per-expert GEMM over slot slabs (256 slots/expert)
__global__ __launch_bounds__(256, 1) void gemm_grouped(const unsigned short* __restrict__ A0,
                                                       const unsigned short* __restrict__ B0,
                                                       int Bstride, EpiArgs epi, int K,
                                                       const int* __restrict__ counts) {
  const int e = blockIdx.y >> 1, rt = blockIdx.y & 1;
  int cnt = counts[e];
  if (cnt > 256) cnt = 256;
  if (rt * 128 >= cnt) return;
  __shared__ __align__(16) unsigned short As[3 * 4096];
  __shared__ __align__(16) unsigned short Bs[3 * 4096];
  const int base = e * 256 + rt * 128;
  epi.out = (void*)((unsigned short*)epi.out + (size_t)base * epi.ldo);
  gemm_tile(A0 + (size_t)base * K, K, B0 + (size_t)e * Bstride, K, K, 0,
            blockIdx.x * 128, epi, As, Bs);
}

// ---------------------------------------------------------------------------
// Router (unchanged)
// ---------------------------------------------------------------------------
__global__ void router_kernel(const float* __restrict__ C1,
                              const float* __restrict__ bias,
                              unsigned short* __restrict__ lat_g,
                              int* __restrict__ counts,
                              int* __restrict__ slot_nk, float* __restrict__ gw_nk,
                              float* __restrict__ zp) {
  const int n = blockIdx.x * 4 + (threadIdx.x >> 6);
  const int lane = threadIdx.x & 63;
  const float* row = C1 + (size_t)n * 384;
  const float logit = row[lane];

  float mx = logit;
#pragma unroll
  for (int d = 32; d; d >>= 1) mx = fmaxf(mx, __shfl_xor(mx, d));
  float se = expf(logit - mx);
#pragma unroll
  for (int d = 32; d; d >>= 1) se += __shfl_xor(se, d);
  if (lane == 0) {
    const float lse = mx + logf(se);
    atomicAdd(zp, 0.001f * lse * lse * (1.f / 1024.f));
  }

  const float aff = 1.f / (1.f + expf(-logit));
  float s = aff + bias[lane];

  float asum = 0.f;
  int e_mine = 0; float a_mine = 0.f;
#pragma unroll
  for (int k = 0; k < 8; ++k) {
    float m2 = s;
#pragma unroll
    for (int d = 32; d; d >>= 1) m2 = fmaxf(m2, __shfl_xor(m2, d));
    const unsigned long long blt = __ballot(s == m2);
    const int idx = __ffsll(blt) - 1;  // lowest index on ties (matches top_k)
    const float a = __shfl(aff, idx);
    asum += a;
    if (lane == k) { e_mine = idx; a_mine = a; }
    if (lane == idx) s = -3.0e38f;
  }
  const float inv = 1.f / (asum + 1e-9f);

  int slot = 0;
  if (lane < 8) {
    int pos = atomicAdd(&counts[e_mine], 1);
    if (pos > 255) pos = 255;
    slot = e_mine * 256 + pos;
    slot_nk[(size_t)n * 8 + lane] = slot;
    gw_nk[(size_t)n * 8 + lane] = a_mine * inv;
  }

  const float4 lv = *(const float4*)(row + 64 + lane * 4);
  const ushort4 lb = make_ushort4(f2bf(lv.x), f2bf(lv.y), f2bf(lv.z), f2bf(lv.w));
#pragma unroll
  for (int k = 0; k < 8; ++k) {
    const int sl = __shfl(slot, k);
    *(ushort4*)(lat_g + (size_t)sl * 256 + lane * 4) = lb;
  }
}

// top-8 weighted combine -> Abuf cols [1024,1280)
__global__ void combine_kernel(const unsigned short* __restrict__ y,
                               const int* __restrict__ slot_nk,
                               const float* __restrict__ gw_nk,
                               unsigned short* __restrict__ Abuf) {
  const int n = blockIdx.x * 4 + (threadIdx.x >> 6);
  const int l4 = (threadIdx.x & 63) * 4;
  float a0 = 0.f, a1 = 0.f, a2 = 0.f, a3 = 0.f;
#pragma unroll
  for (int k = 0; k < 8; ++k) {
    const int sl = slot_nk[(size_t)n * 8 + k];
    const float g = gw_nk[(size_t)n * 8 + k];
    const ushort4 yv = *(const ushort4*)(y + (size_t)sl * 256 + l4);
    a0 += g * bf2f(yv.x); a1 += g * bf2f(yv.y);
    a2 += g * bf2f(yv.z); a3 += g * bf2f(yv.w);
  }
  *(ushort4*)(Abuf + (size_t)n * 1280 + 1024 + l4) =
      make_ushort4(f2bf(a0), f2bf(a1), f2bf(a2), f2bf(a3));
}

// ---------------------------------------------------------------------------
extern "C" void kernel_launch(void* const* d_in, const int* in_sizes, int n_in,
                              void* d_out, int out_size, void* d_ws, size_t ws_size,
                              hipStream_t stream) {
  (void)in_sizes; (void)n_in; (void)out_size; (void)ws_size;
  const float* x      = (const float*)d_in[0];
  const float* gate_w = (const float*)d_in[1];
  const float* bias   = (const float*)d_in[2];
  const float* down_w = (const float*)d_in[3];
  const float* up_w   = (const float*)d_in[4];
  const float* sgu    = (const float*)d_in[5];
  const float* sdw    = (const float*)d_in[6];
  const float* egu    = (const float*)d_in[7];
  const float* edw    = (const float*)d_in[8];
  float* out = (float*)d_out;  // [1024*1024] + z_loss

  char* w = (char*)d_ws;
  auto alloc = [&](size_t bytes) { char* p = w; w += (bytes + 255) & ~(size_t)255; return p; };
  unsigned short* xb    = (unsigned short*)alloc(1048576ull * 2);
  unsigned short* Wcat  = (unsigned short*)alloc(2432ull * 1024 * 2);
  unsigned short* Bf    = (unsigned short*)alloc(1024ull * 1280 * 2);
  unsigned short* egut  = (unsigned short*)alloc(64ull * 512 * 256 * 2);
  unsigned short* edwt  = (unsigned short*)alloc(64ull * 256 * 256 * 2);
  float*          C1    = (float*)alloc(1024ull * 384 * 4);
  unsigned short* Abuf  = (unsigned short*)alloc(1024ull * 1280 * 2);
  unsigned short* lat_g = (unsigned short*)alloc(16384ull * 256 * 2);
  unsigned short* hide  = (unsigned short*)alloc(16384ull * 256 * 2);
  unsigned short* ybuf  = (unsigned short*)alloc(16384ull * 256 * 2);
  int*   counts  = (int*)alloc(64 * 4);
  int*   slot_nk = (int*)alloc(8192 * 4);
  float* gw_nk   = (float*)alloc(8192 * 4);

  // 1. pack everything (+ zero counts and z slot)
  PackArgs pa;
  pa.x = x; pa.gate = gate_w; pa.down = down_w; pa.sgu = sgu; pa.sdw = sdw;
  pa.up = up_w; pa.egu = egu; pa.edw = edw;
  pa.xb = xb; pa.Wcat = Wcat; pa.Bf = Bf; pa.egut = egut; pa.edwt = edwt;
  pa.counts = counts; pa.zp = out + 1048576;
  pack_kernel<<<dim3(13472), dim3(256), 0, stream>>>(pa);

  // 2. gemm1: logits|lat (f32) + fused shared SwiGLU -> Abuf[:,0:1024]
  gemm1_kernel<<<dim3(19, 8), dim3(256), 0, stream>>>(xb, Wcat, C1, Abuf);

  // 3. router
  router_kernel<<<dim3(256), dim3(256), 0, stream>>>(
      C1, bias, lat_g, counts, slot_nk, gw_nk, out + 1048576);

  // 4. grouped GU GEMM + fused SwiGLU -> hide
  {
    EpiArgs e; e.mode = 2; e.out = hide; e.ldo = 256; e.coff = 0;
    gemm_grouped<<<dim3(4, 128), dim3(256), 0, stream>>>(
        lat_g, egut, 512 * 256, e, 256, counts);
  }

  // 5. grouped down GEMM -> ybuf
  {
    EpiArgs e; e.mode = 1; e.out = ybuf; e.ldo = 256; e.coff = 0;
    gemm_grouped<<<dim3(2, 128), dim3(256), 0, stream>>>(
        hide, edwt, 256 * 256, e, 256, counts);
  }

  // 6. combine -> Abuf[:,1024:1280)
  combine_kernel<<<dim3(256), dim3(256), 0, stream>>>(ybuf, slot_nk, gw_nk, Abuf);

  // 7. final fused GEMM (shared-down + routed-up in one K=1280 pass)
  gemm_final<<<dim3(8, 8), dim3(256), 0, stream>>>(Abuf, Bf, out);
}